// Round 3
// baseline (577.951 us; speedup 1.0000x reference)
//
#include <hip/hip_runtime.h>
#include <math.h>

// GraphMemory: E=384, columns CW=E*E=147456.
// t[k,c] = x[k] * (space[k,c] + bias[k,c] + (k==c%E)*kernel[k,c]*x[c/E]/sqrt2)
// out[k] = exp(max_c (t[k,c] - logsumexp_k t[k,c]))
//
// Register-tile version: one WG per 64-column block, 512 threads.
// Thread (rp, cg) owns rows rp*12..rp*12+11 x cols c0+4cg..c0+4cg+3 in VGPRs.
// Column-LSE: per-thread reduce over 12 rows, shfl_xor(16,32) fold over the
// 4 row-parts in a wave, 4KB LDS exchange over the 8 waves.
// Row-max: per-thread over 4 cols, shfl_xor(1,2,4,8) fold over 16 col-groups.

#define E   384
#define CW  (E * E)          // 147456
#define CB  64               // columns per workgroup (256 B per row per array)
#define NWG (CW / CB)        // 2304
#define TPB 512
#define RPT 12               // rows per thread (32 row-parts * 12 = 384)
#define WB  9                // reduce1 w-tiles (9*256 = 2304)
#define KB  6                // reduce1 k-tiles (6*64 = 384)

__device__ __forceinline__ unsigned enc_f32(float v) {
    unsigned u = __float_as_uint(v);
    return (u & 0x80000000u) ? ~u : (u | 0x80000000u);
}
__device__ __forceinline__ float dec_f32(unsigned e) {
    unsigned u = (e & 0x80000000u) ? (e ^ 0x80000000u) : ~e;
    return __uint_as_float(u);
}

__global__ __launch_bounds__(TPB, 4) void gm_main(
    const float* __restrict__ x, const float* __restrict__ kern,
    const float* __restrict__ bias, const float* __restrict__ space,
    float* __restrict__ pw, unsigned* __restrict__ aws, int use_atomic)
{
    __shared__ float pmS[8][CB];      // per-wave per-col partial max
    __shared__ float psS[8][CB];      // per-wave per-col partial sum
    __shared__ float Lc[CB];          // per-col logsumexp

    const int t  = threadIdx.x;
    const int wg = blockIdx.x;
    const int c0 = wg * CB;           // 64 | 384 -> all cols share j
    const int j  = c0 / E;
    const int ls = c0 % E;            // local diag: col cl <-> row ls+cl
    const float xj = x[j] * 0.70710678118654752440f;

    const int cg = t & 15;            // col group: cols c0+4cg .. +3
    const int rp = t >> 4;            // 0..31
    const int r0 = rp * RPT;
    const int w  = t >> 6;            // wave 0..7

    // ---- build 12x4 t-tile in registers (fully static indexing) ----
    float tv[RPT][4];
    #pragma unroll
    for (int i = 0; i < RPT; ++i) {
        const int r = r0 + i;
        const long base = (long)r * CW + c0 + 4 * cg;
        const float4 b4 = *(const float4*)(bias + base);
        const float4 s4 = *(const float4*)(space + base);
        float v0 = b4.x + s4.x, v1 = b4.y + s4.y;
        float v2 = b4.z + s4.z, v3 = b4.w + s4.w;
        const int cl = r - ls;        // diag local col for this row, if in [0,64)
        if (cl >= 4 * cg && cl < 4 * cg + 4) {
            const float kd = kern[(long)r * CW + c0 + cl] * xj;
            if      (cl == 4 * cg)     v0 += kd;
            else if (cl == 4 * cg + 1) v1 += kd;
            else if (cl == 4 * cg + 2) v2 += kd;
            else                       v3 += kd;
        }
        const float xr = x[r];
        tv[i][0] = v0 * xr; tv[i][1] = v1 * xr;
        tv[i][2] = v2 * xr; tv[i][3] = v3 * xr;
    }

    // ---- per-thread column partials (max + sum of exp) ----
    float m[4], s[4];
    #pragma unroll
    for (int e = 0; e < 4; ++e) m[e] = tv[0][e];
    #pragma unroll
    for (int i = 1; i < RPT; ++i) {
        #pragma unroll
        for (int e = 0; e < 4; ++e) m[e] = fmaxf(m[e], tv[i][e]);
    }
    #pragma unroll
    for (int e = 0; e < 4; ++e) s[e] = 0.f;
    #pragma unroll
    for (int i = 0; i < RPT; ++i) {
        #pragma unroll
        for (int e = 0; e < 4; ++e) s[e] += expf(tv[i][e] - m[e]);
    }

    // ---- fold the 4 row-parts within the wave (lane^16, lane^32) ----
    #pragma unroll
    for (int d = 16; d <= 32; d <<= 1) {
        #pragma unroll
        for (int e = 0; e < 4; ++e) {
            const float mo = __shfl_xor(m[e], d);
            const float so = __shfl_xor(s[e], d);
            const float M  = fmaxf(m[e], mo);
            s[e] = s[e] * expf(m[e] - M) + so * expf(mo - M);
            m[e] = M;
        }
    }
    if (((t >> 4) & 3) == 0) {        // one rp per wave writes
        #pragma unroll
        for (int e = 0; e < 4; ++e) {
            pmS[w][4 * cg + e] = m[e];
            psS[w][4 * cg + e] = s[e];
        }
    }
    __syncthreads();

    // ---- final per-column logsumexp over the 8 waves ----
    if (t < CB) {
        float M = -INFINITY;
        #pragma unroll
        for (int p = 0; p < 8; ++p) M = fmaxf(M, pmS[p][t]);
        float S = 0.f;
        #pragma unroll
        for (int p = 0; p < 8; ++p) S += psS[p][t] * expf(pmS[p][t] - M);
        Lc[t] = M + logf(S);
    }
    __syncthreads();

    // ---- row-max over 64 cols: per-thread 4 cols, butterfly over 16 cgs ----
    float lc[4];
    #pragma unroll
    for (int e = 0; e < 4; ++e) lc[e] = Lc[4 * cg + e];
    #pragma unroll
    for (int i = 0; i < RPT; ++i) {
        float v = tv[i][0] - lc[0];
        v = fmaxf(v, tv[i][1] - lc[1]);
        v = fmaxf(v, tv[i][2] - lc[2]);
        v = fmaxf(v, tv[i][3] - lc[3]);
        #pragma unroll
        for (int d = 1; d <= 8; d <<= 1)
            v = fmaxf(v, __shfl_xor(v, d));
        if (cg == 0) {
            if (use_atomic) atomicMax(aws + r0 + i, enc_f32(v));
            else            pw[(long)wg * E + r0 + i] = v;
        }
    }
}

// reduce1: pw[2304][384] -> pw2[9][384]; block = (kb, wb), 256 threads
__global__ __launch_bounds__(256) void gm_reduce1(
    const float* __restrict__ pw, float* __restrict__ pw2)
{
    __shared__ float sm[256];
    const int t  = threadIdx.x;
    const int kb = blockIdx.x % KB;
    const int wb = blockIdx.x / KB;
    const int k  = kb * 64 + (t & 63);
    const int wl = t >> 6;            // 0..3
    float mx = -INFINITY;
    for (int w = wb * 256 + wl; w < wb * 256 + 256; w += 4)
        mx = fmaxf(mx, pw[(long)w * E + k]);
    sm[t] = mx;
    __syncthreads();
    if (t < 64) {
        mx = fmaxf(fmaxf(sm[t], sm[t + 64]), fmaxf(sm[t + 128], sm[t + 192]));
        pw2[wb * E + kb * 64 + t] = mx;
    }
}

// reduce2: pw2[9][384] -> out[384], out[k] = exp(max)
__global__ __launch_bounds__(384) void gm_reduce2(
    const float* __restrict__ pw2, float* __restrict__ out)
{
    const int k = threadIdx.x;
    float mx = -INFINITY;
    #pragma unroll
    for (int wb = 0; wb < WB; ++wb)
        mx = fmaxf(mx, pw2[wb * E + k]);
    out[k] = expf(mx);
}

// fallback finalize for atomic path
__global__ __launch_bounds__(384) void gm_final_atomic(
    const unsigned* __restrict__ aws, float* __restrict__ out)
{
    const int k = threadIdx.x;
    out[k] = expf(dec_f32(aws[k]));
}

extern "C" void kernel_launch(void* const* d_in, const int* in_sizes, int n_in,
                              void* d_out, int out_size, void* d_ws, size_t ws_size,
                              hipStream_t stream)
{
    const float* x     = (const float*)d_in[0];
    const float* kern  = (const float*)d_in[1];
    const float* bias  = (const float*)d_in[2];
    const float* space = (const float*)d_in[3];
    float* out = (float*)d_out;

    const size_t pw_elems = (size_t)NWG * E;
    const size_t need = (pw_elems + (size_t)WB * E) * sizeof(float);

    if (ws_size >= need) {
        float* pw  = (float*)d_ws;
        float* pw2 = pw + pw_elems;
        gm_main<<<NWG, TPB, 0, stream>>>(x, kern, bias, space, pw, nullptr, 0);
        gm_reduce1<<<KB * WB, 256, 0, stream>>>(pw, pw2);
        gm_reduce2<<<1, 384, 0, stream>>>(pw2, out);
    } else {
        unsigned* aws = (unsigned*)d_ws;
        hipMemsetAsync(aws, 0, E * sizeof(unsigned), stream);  // enc(finite) > 0 always
        gm_main<<<NWG, TPB, 0, stream>>>(x, kern, bias, space, nullptr, aws, 1);
        gm_final_atomic<<<1, 384, 0, stream>>>(aws, out);
    }
}